// Round 1
// baseline (151.175 us; speedup 1.0000x reference)
//
#include <hip/hip_runtime.h>

#define TT 12
#define NN 128
#define BB 4
#define PP 14

typedef __attribute__((ext_vector_type(8))) short short8;
typedef __attribute__((ext_vector_type(4))) float f32x4;

__device__ inline unsigned short f2bf(float x){
  unsigned u = __builtin_bit_cast(unsigned, x);
  u += 0x7fffu + ((u >> 16) & 1u);
  return (unsigned short)(u >> 16);
}
__device__ inline float bf2f(unsigned short h){
  unsigned u = ((unsigned)h) << 16;
  return __builtin_bit_cast(float, u);
}
__device__ inline float fexp2(float x){ return __builtin_amdgcn_exp2f(x); }
__device__ inline float sigf(float x){ return __builtin_amdgcn_rcpf(1.0f + fexp2(x * -1.44269504f)); }
__device__ inline float tanh_(float x){ return 1.0f - 2.0f*__builtin_amdgcn_rcpf(1.0f + fexp2(x * 2.88539008f)); }

// Unified LSTM kernel.
// blocks [0,1024): edge LSTM (c*), 64 edge-seqs per WG, writes pre-softmax cij into epi[...,2+j]
// blocks [1024,1032): beta LSTM, blocks [1032,1040): gamma LSTM -> betas_ws/gammas_ws [b][n][p]
__global__ __launch_bounds__(256) void lstm_all(
    const float* __restrict__ x_s,
    const float* __restrict__ bWih, const float* __restrict__ bWhh, const float* __restrict__ bb_,
    const float* __restrict__ bfW,  const float* __restrict__ bfb,
    const float* __restrict__ gWih, const float* __restrict__ gWhh, const float* __restrict__ gb_,
    const float* __restrict__ gfW,  const float* __restrict__ gfb,
    const float* __restrict__ cWih, const float* __restrict__ cWhh, const float* __restrict__ cb_,
    const float* __restrict__ cfW,  const float* __restrict__ cfb,
    float* __restrict__ out_epi,
    float* __restrict__ betas_ws, float* __restrict__ gammas_ws)
{
  __shared__ __align__(16) unsigned short h_lds[64*64];   // [seq][hu] bf16, XOR-swizzled
  __shared__ __align__(16) unsigned short xext[TT*64*8];  // [t][seq][8] bf16: x-inputs|1|0 pad
  __shared__ float fw_lds[PP*64];
  __shared__ float fb_lds[PP];

  const int tid = threadIdx.x;
  const int l = tid & 63, w = tid >> 6;      // wave w owns hidden units [w*16, w*16+16)
  const int col = l & 15, kb = l >> 4;       // MFMA lane decomposition

  int g = blockIdx.x;
  int mode; const float *Wih, *Whh, *bias, *fW, *fb;
  if (g < 1024)      { mode=0; Wih=cWih; Whh=cWhh; bias=cb_; fW=cfW; fb=cfb; }
  else if (g < 1032) { mode=1; g-=1024; Wih=bWih; Whh=bWhh; bias=bb_; fW=bfW; fb=bfb; }
  else               { mode=2; g-=1032; Wih=gWih; Whh=gWhh; bias=gb_; fW=gfW; fb=gfb; }

  int b, i=0, j0=0, n0=0;
  if (mode==0) { b = g >> 8; int rem = g & 255; i = rem >> 1; j0 = (rem & 1) << 6; }
  else         { b = g >> 1; n0 = (g & 1) << 6; }

  // ---- stage per-seq input extension [x | 1 | 0-pad] (bf16) for all timesteps
  for (int task = tid; task < TT*64; task += 256) {
    int t = task >> 6, m = task & 63;
    unsigned short* dst = &xext[(t*64+m)*8];
    float v0=0,v1=0,v2=0,v3=0,v4=0,v5=0,v6=0,v7=0;
    if (mode==0) {
      const float* xi = x_s + ((b*TT + t)*NN + i)*3;
      const float* xj = x_s + ((b*TT + t)*NN + (j0+m))*3;
      v0=xi[0]; v1=xi[1]; v2=xi[2]; v3=xj[0]; v4=xj[1]; v5=xj[2]; v6=1.f;
    } else {
      const float* xn = x_s + ((b*TT + t)*NN + (n0+m))*3;
      v0=xn[0]; v1=xn[1]; v2=xn[2]; v3=1.f;
    }
    dst[0]=f2bf(v0); dst[1]=f2bf(v1); dst[2]=f2bf(v2); dst[3]=f2bf(v3);
    dst[4]=f2bf(v4); dst[5]=f2bf(v5); dst[6]=f2bf(v6); dst[7]=f2bf(v7);
  }
  for (int idx = tid; idx < 64*64; idx += 256) h_lds[idx] = 0;
  for (int idx = tid; idx < PP*64; idx += 256) fw_lds[idx] = fW[idx];
  if (tid < PP) fb_lds[tid] = fb[tid];

  // ---- B fragments in registers. Wave w covers gate columns {g*64 + w*16 + col}
  short8 Bw[4][2]; short8 B2v[4];
  #pragma unroll
  for (int nt = 0; nt < 4; ++nt) {
    int n = nt*64 + w*16 + col;
    #pragma unroll
    for (int kt = 0; kt < 2; ++kt) {
      const float* src = Whh + n*64 + kt*32 + kb*8;
      short8 fr;
      #pragma unroll
      for (int jj = 0; jj < 8; ++jj) fr[jj] = (short)f2bf(src[jj]);
      Bw[nt][kt] = fr;
    }
    short8 b2 = {0,0,0,0,0,0,0,0};
    if (kb == 0) {  // K rows 64..71: [Wih cols | bias | 0]
      if (mode==0) {
        b2[0]=(short)f2bf(Wih[n*6+0]); b2[1]=(short)f2bf(Wih[n*6+1]); b2[2]=(short)f2bf(Wih[n*6+2]);
        b2[3]=(short)f2bf(Wih[n*6+3]); b2[4]=(short)f2bf(Wih[n*6+4]); b2[5]=(short)f2bf(Wih[n*6+5]);
        b2[6]=(short)f2bf(bias[n]);
      } else {
        b2[0]=(short)f2bf(Wih[n*3+0]); b2[1]=(short)f2bf(Wih[n*3+1]); b2[2]=(short)f2bf(Wih[n*3+2]);
        b2[3]=(short)f2bf(bias[n]);
      }
    }
    B2v[nt] = b2;
  }

  __syncthreads();

  float cst[16];
  #pragma unroll
  for (int q = 0; q < 16; ++q) cst[q] = 0.f;

  for (int t = 0; t < TT; ++t) {
    // A fragments: h (K 0..63, swizzled LDS) + x-ext (K 64..95, only k-block 0 nonzero)
    short8 ah[4][2]; short8 ax[4];
    #pragma unroll
    for (int mb = 0; mb < 4; ++mb) {
      int seq = mb*16 + col;
      int sw = (seq & 7) << 4;
      #pragma unroll
      for (int kt = 0; kt < 2; ++kt) {
        int boff = (seq << 7) + ((kt*32 + kb*8) << 1);
        ah[mb][kt] = *(const short8*)((const char*)h_lds + (boff ^ sw));
      }
      short8 z = {0,0,0,0,0,0,0,0};
      if (l < 16) ax[mb] = *(const short8*)&xext[(t*64 + mb*16 + l)*8];
      else        ax[mb] = z;
    }
    __syncthreads();  // all reads of h(t) done before anyone writes h(t+1)

    #pragma unroll
    for (int mb = 0; mb < 4; ++mb) {
      f32x4 a0 = {0.f,0.f,0.f,0.f}, a1 = a0, a2 = a0, a3 = a0;
      a0 = __builtin_amdgcn_mfma_f32_16x16x32_bf16(ah[mb][0], Bw[0][0], a0, 0,0,0);
      a0 = __builtin_amdgcn_mfma_f32_16x16x32_bf16(ah[mb][1], Bw[0][1], a0, 0,0,0);
      a0 = __builtin_amdgcn_mfma_f32_16x16x32_bf16(ax[mb],    B2v[0],   a0, 0,0,0);
      a1 = __builtin_amdgcn_mfma_f32_16x16x32_bf16(ah[mb][0], Bw[1][0], a1, 0,0,0);
      a1 = __builtin_amdgcn_mfma_f32_16x16x32_bf16(ah[mb][1], Bw[1][1], a1, 0,0,0);
      a1 = __builtin_amdgcn_mfma_f32_16x16x32_bf16(ax[mb],    B2v[1],   a1, 0,0,0);
      a2 = __builtin_amdgcn_mfma_f32_16x16x32_bf16(ah[mb][0], Bw[2][0], a2, 0,0,0);
      a2 = __builtin_amdgcn_mfma_f32_16x16x32_bf16(ah[mb][1], Bw[2][1], a2, 0,0,0);
      a2 = __builtin_amdgcn_mfma_f32_16x16x32_bf16(ax[mb],    B2v[2],   a2, 0,0,0);
      a3 = __builtin_amdgcn_mfma_f32_16x16x32_bf16(ah[mb][0], Bw[3][0], a3, 0,0,0);
      a3 = __builtin_amdgcn_mfma_f32_16x16x32_bf16(ah[mb][1], Bw[3][1], a3, 0,0,0);
      a3 = __builtin_amdgcn_mfma_f32_16x16x32_bf16(ax[mb],    B2v[3],   a3, 0,0,0);
      #pragma unroll
      for (int r = 0; r < 4; ++r) {
        float gi = a0[r], gf = a1[r], gg = a2[r], go = a3[r];
        float cc = cst[mb*4+r];
        cc = sigf(gf)*cc + sigf(gi)*tanh_(gg);
        float hh = sigf(go)*tanh_(cc);
        cst[mb*4+r] = cc;
        int seq = mb*16 + kb*4 + r;
        int hu = w*16 + col;
        int boff = ((seq << 7) + (hu << 1)) ^ ((seq & 7) << 4);
        *(unsigned short*)((char*)h_lds + boff) = f2bf(hh);
      }
    }
    __syncthreads();  // h(t+1) complete
  }

  // ---- projection: sigmoid(h_last @ fW.T + fb)
  for (int task = tid; task < 64*PP; task += 256) {
    int seq = task & 63, p = task >> 6;
    int sw = (seq & 7) << 4;
    float dot = fb_lds[p];
    #pragma unroll 8
    for (int k = 0; k < 64; ++k) {
      int boff = ((seq << 7) + (k << 1)) ^ sw;
      dot += bf2f(*(const unsigned short*)((const char*)h_lds + boff)) * fw_lds[p*64+k];
    }
    float val = sigf(dot);
    if (mode==0) {
      out_epi[(size_t)((b*PP + p)*NN + i)*130 + 2 + (j0+seq)] = val;
    } else if (mode==1) {
      betas_ws[(b*NN + n0+seq)*PP + p] = val;
    } else {
      gammas_ws[(b*NN + n0+seq)*PP + p] = val;
    }
  }
}

// softmax over j (in-place in epi rows) + write beta/gamma columns
__global__ __launch_bounds__(256) void softmax_epi(
    const float* __restrict__ betas_ws, const float* __restrict__ gammas_ws,
    float* __restrict__ out_epi)
{
  int row = blockIdx.x*4 + (threadIdx.x >> 6);   // row = (b*14+p)*128 + i
  int l = threadIdx.x & 63;
  int b = row / (PP*NN); int rem = row - b*(PP*NN); int p = rem >> 7; int i = rem & 127;
  float* epi = out_epi + (size_t)row*130;
  float v0 = epi[2+l], v1 = epi[2+64+l];
  float m = fmaxf(v0, v1);
  #pragma unroll
  for (int off = 32; off; off >>= 1) m = fmaxf(m, __shfl_xor(m, off));
  float e0 = fexp2((v0-m)*1.44269504f), e1 = fexp2((v1-m)*1.44269504f);
  float s = e0 + e1;
  #pragma unroll
  for (int off = 32; off; off >>= 1) s += __shfl_xor(s, off);
  float inv = 1.0f / s;
  epi[2+l] = e0*inv; epi[2+64+l] = e1*inv;
  if (l == 0) epi[0] = betas_ws[(b*NN+i)*PP + p];
  if (l == 1) epi[1] = gammas_ws[(b*NN+i)*PP + p];
}

// sequential SIR scan over P steps; one WG per batch, 4 lanes per node
__global__ __launch_bounds__(512) void sir_scan(
    const float* __restrict__ x,
    const float* __restrict__ betas_ws, const float* __restrict__ gammas_ws,
    const float* __restrict__ epi,
    float* __restrict__ out0, float* __restrict__ out2, float* __restrict__ out3)
{
  __shared__ float Ish[NN];
  int b = blockIdx.x;
  int tid = threadIdx.x;
  int i = tid >> 2, q = tid & 3;
  const float* x0 = x + ((b*TT + 11)*NN + i)*3;
  float S = x0[0], I = x0[1], R = x0[2];
  if (q == 0) Ish[i] = I;
  __syncthreads();
  for (int p = 0; p < PP; ++p) {
    const float* crow = epi + (size_t)((b*PP + p)*NN + i)*130 + 2 + q*32;
    float part = 0.f;
    #pragma unroll 8
    for (int j = 0; j < 32; ++j) part += crow[j] * Ish[q*32 + j];
    part += __shfl_xor(part, 1);
    part += __shfl_xor(part, 2);
    __syncthreads();   // all Ish reads done
    if (q == 0) {
      float beta  = betas_ws[(b*NN+i)*PP + p];
      float gamma = gammas_ws[(b*NN+i)*PP + p];
      float Ntot = fmaxf(S+I+R, 1e-8f);
      float dS = -beta*S/Ntot*part;
      float dI = -dS - gamma*I;
      float dR = gamma*I;
      float St = fmaxf(S+dS, 0.f), It = fmaxf(I+dI, 0.f), Rt = fmaxf(R+dR, 0.f);
      float scale = Ntot / fmaxf(St+It+Rt, 1e-8f);
      float Inew = fmaxf(-dS, 0.f);
      int o = (b*PP+p)*NN + i;
      float Sn = St*scale, In = It*scale, Rn = Rt*scale;
      out0[o] = In;
      out2[o*3+0] = Sn; out2[o*3+1] = In; out2[o*3+2] = Rn;
      out3[o] = Inew;
      S = Sn; I = In; R = Rn;
      Ish[i] = I;
    }
    __syncthreads();
  }
}

extern "C" void kernel_launch(void* const* d_in, const int* in_sizes, int n_in,
                              void* d_out, int out_size, void* d_ws, size_t ws_size,
                              hipStream_t stream) {
  const float* x_s  = (const float*)d_in[0];
  const float* x    = (const float*)d_in[1];
  const float* bWih = (const float*)d_in[2];
  const float* bWhh = (const float*)d_in[3];
  const float* bb_  = (const float*)d_in[4];
  const float* bfW  = (const float*)d_in[5];
  const float* bfb  = (const float*)d_in[6];
  const float* gWih = (const float*)d_in[7];
  const float* gWhh = (const float*)d_in[8];
  const float* gb_  = (const float*)d_in[9];
  const float* gfW  = (const float*)d_in[10];
  const float* gfb  = (const float*)d_in[11];
  const float* cWih = (const float*)d_in[12];
  const float* cWhh = (const float*)d_in[13];
  const float* cb_  = (const float*)d_in[14];
  const float* cfW  = (const float*)d_in[15];
  const float* cfb  = (const float*)d_in[16];

  float* out  = (float*)d_out;
  float* out0 = out;                              // (B,P,N,1)
  float* epi  = out + 7168;                       // (B,P,N,130)
  float* out2 = out + 7168 + 931840;              // (B,P,N,3)
  float* out3 = out + 7168 + 931840 + 21504;      // (B,P,N,1)
  float* betas_ws  = (float*)d_ws;                // 7168 f32
  float* gammas_ws = betas_ws + 7168;             // 7168 f32

  hipLaunchKernelGGL(lstm_all, dim3(1040), dim3(256), 0, stream,
      x_s, bWih,bWhh,bb_,bfW,bfb, gWih,gWhh,gb_,gfW,gfb, cWih,cWhh,cb_,cfW,cfb,
      epi, betas_ws, gammas_ws);
  hipLaunchKernelGGL(softmax_epi, dim3(1792), dim3(256), 0, stream,
      betas_ws, gammas_ws, epi);
  hipLaunchKernelGGL(sir_scan, dim3(4), dim3(512), 0, stream,
      x, betas_ws, gammas_ws, epi, out0, out2, out3);
}

// Round 2
// 138.204 us; speedup vs baseline: 1.0939x; 1.0939x over previous
//
#include <hip/hip_runtime.h>

#define TT 12
#define NN 128
#define BB 4
#define PP 14

typedef __attribute__((ext_vector_type(8))) short short8;
typedef __attribute__((ext_vector_type(4))) float f32x4;
typedef __attribute__((ext_vector_type(2))) float float2v;
typedef __attribute__((ext_vector_type(2))) unsigned uint2v;

__device__ inline unsigned short f2bf(float x){
  unsigned u = __builtin_bit_cast(unsigned, x);
  u += 0x7fffu + ((u >> 16) & 1u);
  return (unsigned short)(u >> 16);
}
__device__ inline float bf2f(unsigned short h){
  unsigned u = ((unsigned)h) << 16;
  return __builtin_bit_cast(float, u);
}
__device__ inline float fexp2(float x){ return __builtin_amdgcn_exp2f(x); }
__device__ inline float sigf(float x){ return __builtin_amdgcn_rcpf(1.0f + fexp2(x * -1.44269504f)); }

__device__ inline float2v exp2v(float2v x){
  float2v r; r[0]=__builtin_amdgcn_exp2f(x[0]); r[1]=__builtin_amdgcn_exp2f(x[1]); return r;
}
__device__ inline float2v rcpv(float2v x){
  float2v r; r[0]=__builtin_amdgcn_rcpf(x[0]); r[1]=__builtin_amdgcn_rcpf(x[1]); return r;
}
__device__ inline float2v sig2(float2v x){ return rcpv(1.0f + exp2v(x * -1.44269504f)); }
__device__ inline float2v tanh2(float2v x){ return 1.0f - 2.0f*rcpv(1.0f + exp2v(x * 2.88539008f)); }

// Unified LSTM kernel.
// blocks [0,1024): edge LSTM (c*), 64 edge-seqs per WG, writes pre-softmax cij into epi[...,2+j]
// blocks [1024,1032): beta LSTM, blocks [1032,1040): gamma LSTM -> betas_ws/gammas_ws
// MFMA layout: A = weights (row=gate, k=hu), B = h^T (k=hu, col=seq) -> D[gate][seq].
// Lane (q=l>>4, col=l&15): acc reg r holds gate-sub q*4+r, i.e. hu = w*16+q*4+r, seq = st*16+col.
// -> h-writeback is 4 consecutive hu at fixed seq = one packed ds_write_b64 per seq-tile.
__global__ __launch_bounds__(256) void lstm_all(
    const float* __restrict__ x_s,
    const float* __restrict__ bWih, const float* __restrict__ bWhh, const float* __restrict__ bb_,
    const float* __restrict__ bfW,  const float* __restrict__ bfb,
    const float* __restrict__ gWih, const float* __restrict__ gWhh, const float* __restrict__ gb_,
    const float* __restrict__ gfW,  const float* __restrict__ gfb,
    const float* __restrict__ cWih, const float* __restrict__ cWhh, const float* __restrict__ cb_,
    const float* __restrict__ cfW,  const float* __restrict__ cfb,
    float* __restrict__ out_epi,
    float* __restrict__ betas_ws, float* __restrict__ gammas_ws)
{
  __shared__ __align__(16) char hbuf[2*8192];             // double-buffered h[seq][hu] bf16, XOR-swizzled
  __shared__ __align__(16) unsigned short xext[TT*64*8];  // [t][seq][8] bf16: x-inputs|1|0 pad
  __shared__ float fw_lds[PP*64];
  __shared__ float fb_lds[PP];

  const int tid = threadIdx.x;
  const int l = tid & 63, w = tid >> 6;      // wave w owns hidden units [w*16, w*16+16)
  const int col = l & 15, q = l >> 4;

  int g = blockIdx.x;
  int mode; const float *Wih, *Whh, *bias, *fW, *fb;
  if (g < 1024)      { mode=0; Wih=cWih; Whh=cWhh; bias=cb_; fW=cfW; fb=cfb; }
  else if (g < 1032) { mode=1; g-=1024; Wih=bWih; Whh=bWhh; bias=bb_; fW=bfW; fb=bfb; }
  else               { mode=2; g-=1032; Wih=gWih; Whh=gWhh; bias=gb_; fW=gfW; fb=gfb; }

  int b, i=0, j0=0, n0=0;
  if (mode==0) { b = g >> 8; int rem = g & 255; i = rem >> 1; j0 = (rem & 1) << 6; }
  else         { b = g >> 1; n0 = (g & 1) << 6; }

  // ---- stage per-seq input extension [x | 1 | 0-pad] (bf16) for all timesteps
  for (int task = tid; task < TT*64; task += 256) {
    int t = task >> 6, m = task & 63;
    unsigned short* dst = &xext[(t*64+m)*8];
    float v0=0,v1=0,v2=0,v3=0,v4=0,v5=0,v6=0,v7=0;
    if (mode==0) {
      const float* xi = x_s + ((b*TT + t)*NN + i)*3;
      const float* xj = x_s + ((b*TT + t)*NN + (j0+m))*3;
      v0=xi[0]; v1=xi[1]; v2=xi[2]; v3=xj[0]; v4=xj[1]; v5=xj[2]; v6=1.f;
    } else {
      const float* xn = x_s + ((b*TT + t)*NN + (n0+m))*3;
      v0=xn[0]; v1=xn[1]; v2=xn[2]; v3=1.f;
    }
    dst[0]=f2bf(v0); dst[1]=f2bf(v1); dst[2]=f2bf(v2); dst[3]=f2bf(v3);
    dst[4]=f2bf(v4); dst[5]=f2bf(v5); dst[6]=f2bf(v6); dst[7]=f2bf(v7);
  }
  for (int idx = tid; idx < 2048; idx += 256) ((unsigned*)hbuf)[idx] = 0;  // zero buf0
  for (int idx = tid; idx < PP*64; idx += 256) fw_lds[idx] = fW[idx];
  if (tid < PP) fb_lds[tid] = fb[tid];

  // ---- weights as A-fragments: A[row=gate (l&15)][k = q*8+jj]
  short8 Aw[4][2]; short8 Ax[4];
  #pragma unroll
  for (int gt = 0; gt < 4; ++gt) {
    int gate = gt*64 + w*16 + col;
    #pragma unroll
    for (int kt = 0; kt < 2; ++kt) {
      const float* src = Whh + gate*64 + kt*32 + q*8;
      short8 fr;
      #pragma unroll
      for (int jj = 0; jj < 8; ++jj) fr[jj] = (short)f2bf(src[jj]);
      Aw[gt][kt] = fr;
    }
    short8 ax = {0,0,0,0,0,0,0,0};
    if (q == 0) {  // ext K rows 0..7: [Wih cols | bias | 0]
      if (mode==0) {
        ax[0]=(short)f2bf(Wih[gate*6+0]); ax[1]=(short)f2bf(Wih[gate*6+1]); ax[2]=(short)f2bf(Wih[gate*6+2]);
        ax[3]=(short)f2bf(Wih[gate*6+3]); ax[4]=(short)f2bf(Wih[gate*6+4]); ax[5]=(short)f2bf(Wih[gate*6+5]);
        ax[6]=(short)f2bf(bias[gate]);
      } else {
        ax[0]=(short)f2bf(Wih[gate*3+0]); ax[1]=(short)f2bf(Wih[gate*3+1]); ax[2]=(short)f2bf(Wih[gate*3+2]);
        ax[3]=(short)f2bf(bias[gate]);
      }
    }
    Ax[gt] = ax;
  }

  __syncthreads();

  // per-lane LDS byte offsets (swizzle = (seq&7)<<4, and seq&7 == col&7)
  const int sw = (col & 7) << 4;
  const int r0off = col*128 + ((q*16) ^ sw);           // B-frag kt=0: 8 hu at q*8
  const int r1off = col*128 + ((64 + q*16) ^ sw);      // B-frag kt=1
  const int wroff = col*128 + (((w*32) + q*8) ^ sw);   // h-write: hu quad w*16+q*4

  float2v cstv[8];
  #pragma unroll
  for (int z = 0; z < 8; ++z) cstv[z] = (float2v){0.f, 0.f};

  const short8 zero8 = {0,0,0,0,0,0,0,0};

  for (int t = 0; t < TT; ++t) {
    const char* rb = hbuf + ((t & 1) ? 8192 : 0);
    char* wbp      = hbuf + ((t & 1) ? 0 : 8192);
    #pragma unroll
    for (int st = 0; st < 4; ++st) {
      short8 b0 = *(const short8*)(rb + st*2048 + r0off);
      short8 b1 = *(const short8*)(rb + st*2048 + r1off);
      short8 bx = zero8;
      if (l < 16) bx = *(const short8*)&xext[(t*64 + st*16 + col)*8];
      f32x4 A0 = {0.f,0.f,0.f,0.f}, A1 = A0, A2 = A0, A3 = A0;
      A0 = __builtin_amdgcn_mfma_f32_16x16x32_bf16(Aw[0][0], b0, A0, 0,0,0);
      A0 = __builtin_amdgcn_mfma_f32_16x16x32_bf16(Aw[0][1], b1, A0, 0,0,0);
      A0 = __builtin_amdgcn_mfma_f32_16x16x32_bf16(Ax[0],    bx, A0, 0,0,0);
      A1 = __builtin_amdgcn_mfma_f32_16x16x32_bf16(Aw[1][0], b0, A1, 0,0,0);
      A1 = __builtin_amdgcn_mfma_f32_16x16x32_bf16(Aw[1][1], b1, A1, 0,0,0);
      A1 = __builtin_amdgcn_mfma_f32_16x16x32_bf16(Ax[1],    bx, A1, 0,0,0);
      A2 = __builtin_amdgcn_mfma_f32_16x16x32_bf16(Aw[2][0], b0, A2, 0,0,0);
      A2 = __builtin_amdgcn_mfma_f32_16x16x32_bf16(Aw[2][1], b1, A2, 0,0,0);
      A2 = __builtin_amdgcn_mfma_f32_16x16x32_bf16(Ax[2],    bx, A2, 0,0,0);
      A3 = __builtin_amdgcn_mfma_f32_16x16x32_bf16(Aw[3][0], b0, A3, 0,0,0);
      A3 = __builtin_amdgcn_mfma_f32_16x16x32_bf16(Aw[3][1], b1, A3, 0,0,0);
      A3 = __builtin_amdgcn_mfma_f32_16x16x32_bf16(Ax[3],    bx, A3, 0,0,0);

      float2v i0 = {A0[0],A0[1]}, i1 = {A0[2],A0[3]};
      float2v f0 = {A1[0],A1[1]}, f1 = {A1[2],A1[3]};
      float2v g0 = {A2[0],A2[1]}, g1 = {A2[2],A2[3]};
      float2v o0 = {A3[0],A3[1]}, o1 = {A3[2],A3[3]};
      float2v c0 = cstv[st*2+0], c1 = cstv[st*2+1];
      c0 = sig2(f0)*c0 + sig2(i0)*tanh2(g0);
      c1 = sig2(f1)*c1 + sig2(i1)*tanh2(g1);
      cstv[st*2+0] = c0; cstv[st*2+1] = c1;
      float2v h0 = sig2(o0)*tanh2(c0);
      float2v h1 = sig2(o1)*tanh2(c1);
      unsigned plo, phi;
      asm("v_cvt_pk_bf16_f32 %0, %1, %2" : "=v"(plo) : "v"(h0[0]), "v"(h0[1]));
      asm("v_cvt_pk_bf16_f32 %0, %1, %2" : "=v"(phi) : "v"(h1[0]), "v"(h1[1]));
      uint2v pv = {plo, phi};
      *(uint2v*)(wbp + st*2048 + wroff) = pv;   // ds_write_b64, conflict-free
    }
    __syncthreads();   // h(t+1) complete; also fences re-use of the read buffer
  }

  // ---- projection: sigmoid(h_last @ fW.T + fb); h(12) is in buf0
  const char* hfin = hbuf;
  for (int task = tid; task < 64*PP; task += 256) {
    int seq = task & 63, p = task >> 6;
    int sw2 = (seq & 7) << 4;
    float dot = fb_lds[p];
    #pragma unroll
    for (int kc = 0; kc < 8; ++kc) {
      short8 v = *(const short8*)(hfin + ((seq*128 + kc*16) ^ sw2));
      #pragma unroll
      for (int jj = 0; jj < 8; ++jj)
        dot += bf2f((unsigned short)v[jj]) * fw_lds[p*64 + kc*8 + jj];
    }
    float val = sigf(dot);
    if (mode==0) {
      out_epi[(size_t)((b*PP + p)*NN + i)*130 + 2 + (j0+seq)] = val;
    } else if (mode==1) {
      betas_ws[(b*NN + n0+seq)*PP + p] = val;
    } else {
      gammas_ws[(b*NN + n0+seq)*PP + p] = val;
    }
  }
}

// softmax over j (in-place in epi rows) + write beta/gamma columns
__global__ __launch_bounds__(256) void softmax_epi(
    const float* __restrict__ betas_ws, const float* __restrict__ gammas_ws,
    float* __restrict__ out_epi)
{
  int row = blockIdx.x*4 + (threadIdx.x >> 6);   // row = (b*14+p)*128 + i
  int l = threadIdx.x & 63;
  int b = row / (PP*NN); int rem = row - b*(PP*NN); int p = rem >> 7; int i = rem & 127;
  float* epi = out_epi + (size_t)row*130;
  float v0 = epi[2+l], v1 = epi[2+64+l];
  float m = fmaxf(v0, v1);
  #pragma unroll
  for (int off = 32; off; off >>= 1) m = fmaxf(m, __shfl_xor(m, off));
  float e0 = fexp2((v0-m)*1.44269504f), e1 = fexp2((v1-m)*1.44269504f);
  float s = e0 + e1;
  #pragma unroll
  for (int off = 32; off; off >>= 1) s += __shfl_xor(s, off);
  float inv = 1.0f / s;
  epi[2+l] = e0*inv; epi[2+64+l] = e1*inv;
  if (l == 0) epi[0] = betas_ws[(b*NN+i)*PP + p];
  if (l == 1) epi[1] = gammas_ws[(b*NN+i)*PP + p];
}

// sequential SIR scan over P steps; one WG per batch, 4 lanes per node
__global__ __launch_bounds__(512) void sir_scan(
    const float* __restrict__ x,
    const float* __restrict__ betas_ws, const float* __restrict__ gammas_ws,
    const float* __restrict__ epi,
    float* __restrict__ out0, float* __restrict__ out2, float* __restrict__ out3)
{
  __shared__ float Ish[NN];
  int b = blockIdx.x;
  int tid = threadIdx.x;
  int i = tid >> 2, q = tid & 3;
  const float* x0 = x + ((b*TT + 11)*NN + i)*3;
  float S = x0[0], I = x0[1], R = x0[2];
  if (q == 0) Ish[i] = I;
  __syncthreads();
  for (int p = 0; p < PP; ++p) {
    const float* crow = epi + (size_t)((b*PP + p)*NN + i)*130 + 2 + q*32;
    float part = 0.f;
    #pragma unroll 8
    for (int j = 0; j < 32; ++j) part += crow[j] * Ish[q*32 + j];
    part += __shfl_xor(part, 1);
    part += __shfl_xor(part, 2);
    __syncthreads();   // all Ish reads done
    if (q == 0) {
      float beta  = betas_ws[(b*NN+i)*PP + p];
      float gamma = gammas_ws[(b*NN+i)*PP + p];
      float Ntot = fmaxf(S+I+R, 1e-8f);
      float dS = -beta*S/Ntot*part;
      float dI = -dS - gamma*I;
      float dR = gamma*I;
      float St = fmaxf(S+dS, 0.f), It = fmaxf(I+dI, 0.f), Rt = fmaxf(R+dR, 0.f);
      float scale = Ntot / fmaxf(St+It+Rt, 1e-8f);
      float Inew = fmaxf(-dS, 0.f);
      int o = (b*PP+p)*NN + i;
      float Sn = St*scale, In = It*scale, Rn = Rt*scale;
      out0[o] = In;
      out2[o*3+0] = Sn; out2[o*3+1] = In; out2[o*3+2] = Rn;
      out3[o] = Inew;
      S = Sn; I = In; R = Rn;
      Ish[i] = I;
    }
    __syncthreads();
  }
}

extern "C" void kernel_launch(void* const* d_in, const int* in_sizes, int n_in,
                              void* d_out, int out_size, void* d_ws, size_t ws_size,
                              hipStream_t stream) {
  const float* x_s  = (const float*)d_in[0];
  const float* x    = (const float*)d_in[1];
  const float* bWih = (const float*)d_in[2];
  const float* bWhh = (const float*)d_in[3];
  const float* bb_  = (const float*)d_in[4];
  const float* bfW  = (const float*)d_in[5];
  const float* bfb  = (const float*)d_in[6];
  const float* gWih = (const float*)d_in[7];
  const float* gWhh = (const float*)d_in[8];
  const float* gb_  = (const float*)d_in[9];
  const float* gfW  = (const float*)d_in[10];
  const float* gfb  = (const float*)d_in[11];
  const float* cWih = (const float*)d_in[12];
  const float* cWhh = (const float*)d_in[13];
  const float* cb_  = (const float*)d_in[14];
  const float* cfW  = (const float*)d_in[15];
  const float* cfb  = (const float*)d_in[16];

  float* out  = (float*)d_out;
  float* out0 = out;                              // (B,P,N,1)
  float* epi  = out + 7168;                       // (B,P,N,130)
  float* out2 = out + 7168 + 931840;              // (B,P,N,3)
  float* out3 = out + 7168 + 931840 + 21504;      // (B,P,N,1)
  float* betas_ws  = (float*)d_ws;                // 7168 f32
  float* gammas_ws = betas_ws + 7168;             // 7168 f32

  hipLaunchKernelGGL(lstm_all, dim3(1040), dim3(256), 0, stream,
      x_s, bWih,bWhh,bb_,bfW,bfb, gWih,gWhh,gb_,gfW,gfb, cWih,cWhh,cb_,cfW,cfb,
      epi, betas_ws, gammas_ws);
  hipLaunchKernelGGL(softmax_epi, dim3(1792), dim3(256), 0, stream,
      betas_ws, gammas_ws, epi);
  hipLaunchKernelGGL(sir_scan, dim3(4), dim3(512), 0, stream,
      x, betas_ws, gammas_ws, epi, out0, out2, out3);
}

// Round 3
// 114.635 us; speedup vs baseline: 1.3188x; 1.2056x over previous
//
#include <hip/hip_runtime.h>

#define TT 12
#define NN 128
#define BB 4
#define PP 14

typedef __attribute__((ext_vector_type(8))) short short8;
typedef __attribute__((ext_vector_type(4))) float f32x4;
typedef __attribute__((ext_vector_type(2))) float float2v;
typedef __attribute__((ext_vector_type(2))) unsigned uint2v;

__device__ inline unsigned short f2bf(float x){
  unsigned u = __builtin_bit_cast(unsigned, x);
  u += 0x7fffu + ((u >> 16) & 1u);
  return (unsigned short)(u >> 16);
}
__device__ inline float bf2f(unsigned short h){
  unsigned u = ((unsigned)h) << 16;
  return __builtin_bit_cast(float, u);
}
__device__ inline float fexp2(float x){ return __builtin_amdgcn_exp2f(x); }
__device__ inline float sigf(float x){ return __builtin_amdgcn_rcpf(1.0f + fexp2(x * -1.44269504f)); }

__device__ inline float2v exp2v(float2v x){
  float2v r; r[0]=__builtin_amdgcn_exp2f(x[0]); r[1]=__builtin_amdgcn_exp2f(x[1]); return r;
}
__device__ inline float2v rcpv(float2v x){
  float2v r; r[0]=__builtin_amdgcn_rcpf(x[0]); r[1]=__builtin_amdgcn_rcpf(x[1]); return r;
}
__device__ inline float2v sig2(float2v x){ return rcpv(1.0f + exp2v(x * -1.44269504f)); }
__device__ inline float2v tanh2(float2v x){ return 1.0f - 2.0f*rcpv(1.0f + exp2v(x * 2.88539008f)); }

// Unified LSTM kernel, 16 sequences per block (4 waves x 16 hu each).
// blocks [0,4096): edge LSTM (c*): b = g>>10, i = (g&1023)>>3, j0 = (g&7)*16
// blocks [4096,4128): beta LSTM;  [4128,4160): gamma LSTM
// MFMA layout: A = weights (row=gate, k=hu), B = h^T (k=hu, col=seq) -> D[gate][seq].
// Lane (q=l>>4, col=l&15): acc reg r holds hu = w*16+q*4+r, seq = col.
// h LDS layout: byte(seq,hu) = seq*128 + ((hu*2 + 16*(seq&7)) & 127)   [rotate swizzle]
//   -> b128 h-reads are exactly 8 lanes per bank-quad (optimal), b64 writes 4-way.
__global__ __launch_bounds__(256) void lstm_all(
    const float* __restrict__ x_s,
    const float* __restrict__ bWih, const float* __restrict__ bWhh, const float* __restrict__ bb_,
    const float* __restrict__ bfW,  const float* __restrict__ bfb,
    const float* __restrict__ gWih, const float* __restrict__ gWhh, const float* __restrict__ gb_,
    const float* __restrict__ gfW,  const float* __restrict__ gfb,
    const float* __restrict__ cWih, const float* __restrict__ cWhh, const float* __restrict__ cb_,
    const float* __restrict__ cfW,  const float* __restrict__ cfb,
    float* __restrict__ out_epi,
    float* __restrict__ betas_ws, float* __restrict__ gammas_ws)
{
  __shared__ __align__(16) char hbuf[2*2048];             // double-buffered h[16 seq][64 hu] bf16, rotate-swizzled
  __shared__ __align__(16) unsigned short xext[TT*16*8];  // [t][seq][8] bf16: x-inputs|1|0 pad
  __shared__ float fw_lds[PP*64];
  __shared__ float fb_lds[PP];

  const int tid = threadIdx.x;
  const int l = tid & 63, w = tid >> 6;      // wave w owns hidden units [w*16, w*16+16)
  const int col = l & 15, q = l >> 4;

  int g = blockIdx.x;
  int mode; const float *Wih, *Whh, *bias, *fW, *fb;
  if (g < 4096)      { mode=0; Wih=cWih; Whh=cWhh; bias=cb_; fW=cfW; fb=cfb; }
  else if (g < 4128) { mode=1; g-=4096; Wih=bWih; Whh=bWhh; bias=bb_; fW=bfW; fb=bfb; }
  else               { mode=2; g-=4128; Wih=gWih; Whh=gWhh; bias=gb_; fW=gfW; fb=gfb; }

  int b, i=0, j0=0, n0=0;
  if (mode==0) { b = g >> 10; int rem = g & 1023; i = rem >> 3; j0 = (rem & 7) << 4; }
  else         { b = g >> 3; n0 = (g & 7) << 4; }

  // ---- stage per-seq input extension [x | 1 | 0-pad] (bf16) for all timesteps
  for (int task = tid; task < TT*16; task += 256) {
    int t = task >> 4, m = task & 15;
    unsigned short* dst = &xext[(t*16+m)*8];
    float v0=0,v1=0,v2=0,v3=0,v4=0,v5=0,v6=0,v7=0;
    if (mode==0) {
      const float* xi = x_s + ((b*TT + t)*NN + i)*3;
      const float* xj = x_s + ((b*TT + t)*NN + (j0+m))*3;
      v0=xi[0]; v1=xi[1]; v2=xi[2]; v3=xj[0]; v4=xj[1]; v5=xj[2]; v6=1.f;
    } else {
      const float* xn = x_s + ((b*TT + t)*NN + (n0+m))*3;
      v0=xn[0]; v1=xn[1]; v2=xn[2]; v3=1.f;
    }
    dst[0]=f2bf(v0); dst[1]=f2bf(v1); dst[2]=f2bf(v2); dst[3]=f2bf(v3);
    dst[4]=f2bf(v4); dst[5]=f2bf(v5); dst[6]=f2bf(v6); dst[7]=f2bf(v7);
  }
  for (int idx = tid; idx < 512; idx += 256) ((unsigned*)hbuf)[idx] = 0;  // zero buf0
  for (int idx = tid; idx < PP*64; idx += 256) fw_lds[idx] = fW[idx];
  if (tid < PP) fb_lds[tid] = fb[tid];

  // ---- weights as A-fragments: A[row=gate (l&15)][k = q*8+jj]
  short8 Aw[4][2]; short8 Ax[4];
  #pragma unroll
  for (int gt = 0; gt < 4; ++gt) {
    int gate = gt*64 + w*16 + col;
    #pragma unroll
    for (int kt = 0; kt < 2; ++kt) {
      const float* src = Whh + gate*64 + kt*32 + q*8;
      short8 fr;
      #pragma unroll
      for (int jj = 0; jj < 8; ++jj) fr[jj] = (short)f2bf(src[jj]);
      Aw[gt][kt] = fr;
    }
    short8 ax = {0,0,0,0,0,0,0,0};
    if (q == 0) {  // ext K rows 0..7: [Wih cols | bias | 0]
      if (mode==0) {
        ax[0]=(short)f2bf(Wih[gate*6+0]); ax[1]=(short)f2bf(Wih[gate*6+1]); ax[2]=(short)f2bf(Wih[gate*6+2]);
        ax[3]=(short)f2bf(Wih[gate*6+3]); ax[4]=(short)f2bf(Wih[gate*6+4]); ax[5]=(short)f2bf(Wih[gate*6+5]);
        ax[6]=(short)f2bf(bias[gate]);
      } else {
        ax[0]=(short)f2bf(Wih[gate*3+0]); ax[1]=(short)f2bf(Wih[gate*3+1]); ax[2]=(short)f2bf(Wih[gate*3+2]);
        ax[3]=(short)f2bf(bias[gate]);
      }
    }
    Ax[gt] = ax;
  }

  __syncthreads();

  // per-lane LDS byte offsets (rotate swizzle by 16*(seq&7) mod 128; seq == col)
  const int rot = (col & 7) << 4;
  const int r0off = col*128 + ((  0 + (q<<4) + rot) & 127);   // B-frag kt=0: 8 hu at q*8
  const int r1off = col*128 + (( 64 + (q<<4) + rot) & 127);   // B-frag kt=1
  const int wroff = col*128 + ((w*32 + q*8 + rot) & 127);     // h-write: hu quad w*16+q*4

  float2v c0 = {0.f,0.f}, c1 = {0.f,0.f};
  const short8 zero8 = {0,0,0,0,0,0,0,0};

  for (int t = 0; t < TT; ++t) {
    const char* rb = hbuf + ((t & 1) ? 2048 : 0);
    char* wbp      = hbuf + ((t & 1) ? 0 : 2048);
    short8 b0 = *(const short8*)(rb + r0off);
    short8 b1 = *(const short8*)(rb + r1off);
    short8 bx = zero8;
    if (l < 16) bx = *(const short8*)&xext[(t*16 + col)*8];
    f32x4 A0 = {0.f,0.f,0.f,0.f}, A1 = A0, A2 = A0, A3 = A0;
    A0 = __builtin_amdgcn_mfma_f32_16x16x32_bf16(Aw[0][0], b0, A0, 0,0,0);
    A0 = __builtin_amdgcn_mfma_f32_16x16x32_bf16(Aw[0][1], b1, A0, 0,0,0);
    A0 = __builtin_amdgcn_mfma_f32_16x16x32_bf16(Ax[0],    bx, A0, 0,0,0);
    A1 = __builtin_amdgcn_mfma_f32_16x16x32_bf16(Aw[1][0], b0, A1, 0,0,0);
    A1 = __builtin_amdgcn_mfma_f32_16x16x32_bf16(Aw[1][1], b1, A1, 0,0,0);
    A1 = __builtin_amdgcn_mfma_f32_16x16x32_bf16(Ax[1],    bx, A1, 0,0,0);
    A2 = __builtin_amdgcn_mfma_f32_16x16x32_bf16(Aw[2][0], b0, A2, 0,0,0);
    A2 = __builtin_amdgcn_mfma_f32_16x16x32_bf16(Aw[2][1], b1, A2, 0,0,0);
    A2 = __builtin_amdgcn_mfma_f32_16x16x32_bf16(Ax[2],    bx, A2, 0,0,0);
    A3 = __builtin_amdgcn_mfma_f32_16x16x32_bf16(Aw[3][0], b0, A3, 0,0,0);
    A3 = __builtin_amdgcn_mfma_f32_16x16x32_bf16(Aw[3][1], b1, A3, 0,0,0);
    A3 = __builtin_amdgcn_mfma_f32_16x16x32_bf16(Ax[3],    bx, A3, 0,0,0);

    float2v i0 = {A0[0],A0[1]}, i1 = {A0[2],A0[3]};
    float2v f0 = {A1[0],A1[1]}, f1 = {A1[2],A1[3]};
    float2v g0 = {A2[0],A2[1]}, g1 = {A2[2],A2[3]};
    float2v o0 = {A3[0],A3[1]}, o1 = {A3[2],A3[3]};
    c0 = sig2(f0)*c0 + sig2(i0)*tanh2(g0);
    c1 = sig2(f1)*c1 + sig2(i1)*tanh2(g1);
    float2v h0 = sig2(o0)*tanh2(c0);
    float2v h1 = sig2(o1)*tanh2(c1);
    unsigned plo, phi;
    asm("v_cvt_pk_bf16_f32 %0, %1, %2" : "=v"(plo) : "v"(h0[0]), "v"(h0[1]));
    asm("v_cvt_pk_bf16_f32 %0, %1, %2" : "=v"(phi) : "v"(h1[0]), "v"(h1[1]));
    uint2v pv = {plo, phi};
    *(uint2v*)(wbp + wroff) = pv;   // ds_write_b64
    __syncthreads();   // h(t+1) complete; also fences re-use of the read buffer
  }

  // ---- projection: sigmoid(h_last @ fW.T + fb); h(12) is in buf0
  const char* hfin = hbuf;
  for (int task = tid; task < 16*PP; task += 256) {
    int seq = task & 15, p = task >> 4;
    int rot2 = (seq & 7) << 4;
    float dot = fb_lds[p];
    #pragma unroll
    for (int kc = 0; kc < 8; ++kc) {
      short8 v = *(const short8*)(hfin + seq*128 + (((kc<<4) + rot2) & 127));
      #pragma unroll
      for (int jj = 0; jj < 8; ++jj)
        dot += bf2f((unsigned short)v[jj]) * fw_lds[p*64 + kc*8 + jj];
    }
    float val = sigf(dot);
    if (mode==0) {
      out_epi[(size_t)((b*PP + p)*NN + i)*130 + 2 + (j0+seq)] = val;
    } else if (mode==1) {
      betas_ws[(b*NN + n0+seq)*PP + p] = val;
    } else {
      gammas_ws[(b*NN + n0+seq)*PP + p] = val;
    }
  }
}

// softmax over j (in-place in epi rows) + write beta/gamma columns
__global__ __launch_bounds__(256) void softmax_epi(
    const float* __restrict__ betas_ws, const float* __restrict__ gammas_ws,
    float* __restrict__ out_epi)
{
  int row = blockIdx.x*4 + (threadIdx.x >> 6);   // row = (b*14+p)*128 + i
  int l = threadIdx.x & 63;
  int b = row / (PP*NN); int rem = row - b*(PP*NN); int p = rem >> 7; int i = rem & 127;
  float* epi = out_epi + (size_t)row*130;
  float v0 = epi[2+l], v1 = epi[2+64+l];
  float m = fmaxf(v0, v1);
  #pragma unroll
  for (int off = 32; off; off >>= 1) m = fmaxf(m, __shfl_xor(m, off));
  float e0 = fexp2((v0-m)*1.44269504f), e1 = fexp2((v1-m)*1.44269504f);
  float s = e0 + e1;
  #pragma unroll
  for (int off = 32; off; off >>= 1) s += __shfl_xor(s, off);
  float inv = 1.0f / s;
  epi[2+l] = e0*inv; epi[2+64+l] = e1*inv;
  if (l == 0) epi[0] = betas_ws[(b*NN+i)*PP + p];
  if (l == 1) epi[1] = gammas_ws[(b*NN+i)*PP + p];
}

// sequential SIR scan over P steps; one WG per batch, 8 lanes per node, float2 loads
__global__ __launch_bounds__(1024) void sir_scan(
    const float* __restrict__ x,
    const float* __restrict__ betas_ws, const float* __restrict__ gammas_ws,
    const float* __restrict__ epi,
    float* __restrict__ out0, float* __restrict__ out2, float* __restrict__ out3)
{
  __shared__ float Ish[NN];
  int b = blockIdx.x;
  int tid = threadIdx.x;
  int i = tid >> 3, q = tid & 7;
  const float* x0 = x + ((b*TT + 11)*NN + i)*3;
  float S = x0[0], I = x0[1], R = x0[2];
  if (q == 0) Ish[i] = I;
  __syncthreads();
  for (int p = 0; p < PP; ++p) {
    const float* crow = epi + (size_t)((b*PP + p)*NN + i)*130 + 2 + q*16;
    float part = 0.f;
    #pragma unroll
    for (int jj = 0; jj < 8; ++jj) {
      float2v v = *(const float2v*)(crow + jj*2);
      part += v[0]*Ish[q*16 + jj*2] + v[1]*Ish[q*16 + jj*2 + 1];
    }
    part += __shfl_xor(part, 1);
    part += __shfl_xor(part, 2);
    part += __shfl_xor(part, 4);
    __syncthreads();   // all Ish reads done
    if (q == 0) {
      float beta  = betas_ws[(b*NN+i)*PP + p];
      float gamma = gammas_ws[(b*NN+i)*PP + p];
      float Ntot = fmaxf(S+I+R, 1e-8f);
      float dS = -beta*S/Ntot*part;
      float dI = -dS - gamma*I;
      float dR = gamma*I;
      float St = fmaxf(S+dS, 0.f), It = fmaxf(I+dI, 0.f), Rt = fmaxf(R+dR, 0.f);
      float scale = Ntot / fmaxf(St+It+Rt, 1e-8f);
      float Inew = fmaxf(-dS, 0.f);
      int o = (b*PP+p)*NN + i;
      float Sn = St*scale, In = It*scale, Rn = Rt*scale;
      out0[o] = In;
      out2[o*3+0] = Sn; out2[o*3+1] = In; out2[o*3+2] = Rn;
      out3[o] = Inew;
      S = Sn; I = In; R = Rn;
      Ish[i] = I;
    }
    __syncthreads();
  }
}

extern "C" void kernel_launch(void* const* d_in, const int* in_sizes, int n_in,
                              void* d_out, int out_size, void* d_ws, size_t ws_size,
                              hipStream_t stream) {
  const float* x_s  = (const float*)d_in[0];
  const float* x    = (const float*)d_in[1];
  const float* bWih = (const float*)d_in[2];
  const float* bWhh = (const float*)d_in[3];
  const float* bb_  = (const float*)d_in[4];
  const float* bfW  = (const float*)d_in[5];
  const float* bfb  = (const float*)d_in[6];
  const float* gWih = (const float*)d_in[7];
  const float* gWhh = (const float*)d_in[8];
  const float* gb_  = (const float*)d_in[9];
  const float* gfW  = (const float*)d_in[10];
  const float* gfb  = (const float*)d_in[11];
  const float* cWih = (const float*)d_in[12];
  const float* cWhh = (const float*)d_in[13];
  const float* cb_  = (const float*)d_in[14];
  const float* cfW  = (const float*)d_in[15];
  const float* cfb  = (const float*)d_in[16];

  float* out  = (float*)d_out;
  float* out0 = out;                              // (B,P,N,1)
  float* epi  = out + 7168;                       // (B,P,N,130)
  float* out2 = out + 7168 + 931840;              // (B,P,N,3)
  float* out3 = out + 7168 + 931840 + 21504;      // (B,P,N,1)
  float* betas_ws  = (float*)d_ws;                // 7168 f32
  float* gammas_ws = betas_ws + 7168;             // 7168 f32

  hipLaunchKernelGGL(lstm_all, dim3(4160), dim3(256), 0, stream,
      x_s, bWih,bWhh,bb_,bfW,bfb, gWih,gWhh,gb_,gfW,gfb, cWih,cWhh,cb_,cfW,cfb,
      epi, betas_ws, gammas_ws);
  hipLaunchKernelGGL(softmax_epi, dim3(1792), dim3(256), 0, stream,
      betas_ws, gammas_ws, epi);
  hipLaunchKernelGGL(sir_scan, dim3(4), dim3(1024), 0, stream,
      x, betas_ws, gammas_ws, epi, out0, out2, out3);
}